// Round 12
// baseline (383.507 us; speedup 1.0000x reference)
//
#include <hip/hip_runtime.h>
#include <hip/hip_bf16.h>

typedef unsigned char u8;
typedef unsigned short u16;
typedef unsigned int u32;
typedef long long s64;
typedef float f32x4 __attribute__((ext_vector_type(4)));
typedef long long s64x2 __attribute__((ext_vector_type(2)));

#define MEM    2000
#define FEA    256
#define SLSTR  2064      // fp8 a row stride (bytes), 16B-aligned
#define OSTR   265       // out-stage row stride (f32)
#define XRS    264       // xr fp8 row stride (bytes)
#define POOLSZ 66048     // a-matrix 32*SLSTR; xr + out-stage overlap inside
#define OUTN   8388608   // 32*256*32*32
#define LSC    0.015625f // logit scale: logit = acc * LSC

// exact f32 -> e4m3fn (RNE) incl subnormals
__device__ __forceinline__ u32 f2e4m3(float x) {
    float ax = fabsf(x);
    u32 s = (__builtin_bit_cast(u32, x) >> 24) & 0x80u;
    if (ax >= 448.f) return s | 0x7e;
    if (ax < 0.015625f) {
        int q = (int)rintf(ax * 512.f);
        return s | (u32)q;
    }
    int e = (int)(__builtin_bit_cast(u32, ax) >> 23) - 127;
    float scale = __builtin_bit_cast(float, (u32)((127 - e + 3) << 23));
    int q = (int)rintf(ax * scale);
    int E = e + 7;
    if (q == 16) { q = 8; E += 1; if (E > 15) return s | 0x7e; }
    return s | (u32)(E << 3) | (u32)(q & 7);
}
// fast f32 -> e4m3fn for v in {0} U [0.15, 64]
__device__ __forceinline__ u32 f2e4m3_fast(float v) {
    u32 u = __builtin_bit_cast(u32, v);
    u += 0x0007FFFFu + ((u >> 20) & 1u);
    int bb = (int)(u >> 20) - 0x3C0;
    return bb < 0 ? 0u : (u32)bb;
}

// ---------------- prep (identical to round 10) ----------------
__global__ __launch_bounds__(256) void prep_kernel(const float* __restrict__ W,
                                                   u8* __restrict__ WTc,
                                                   u8* __restrict__ Wc,
                                                   float* __restrict__ sqv,
                                                   float* __restrict__ loss) {
    const int blk = blockIdx.x, t = threadIdx.x;
    const int m0 = blk * 8;
    {
        const int sl = t >> 5, cl = t & 31;
        const int slot = m0 + sl;
        const int ch0 = cl * 8;
        const float* wr = W + slot * 256 + ch0;
        f32x4 v0 = *(const f32x4*)wr;
        f32x4 v1 = *(const f32x4*)(wr + 4);
        float ss = v0[0]*v0[0] + v0[1]*v0[1] + v0[2]*v0[2] + v0[3]*v0[3]
                 + v1[0]*v1[0] + v1[1]*v1[1] + v1[2]*v1[2] + v1[3]*v1[3];
        ss += __shfl_xor(ss, 1); ss += __shfl_xor(ss, 2); ss += __shfl_xor(ss, 4);
        ss += __shfl_xor(ss, 8); ss += __shfl_xor(ss, 16);
        if (cl == 0) sqv[slot] = ss;
        const int c = slot >> 6, s = slot & 63;
        const int kk = cl >> 2, agp = cl & 3;
        const int kp = kk >> 1, klo = kk & 1;
        u32 lo = 0, hi = 0;
#pragma unroll
        for (int i = 0; i < 4; ++i) {
            lo |= f2e4m3(v0[i] * 16.f) << (i * 8);
            hi |= f2e4m3(v1[i] * 16.f) << (i * 8);
        }
        u8* dst = Wc + c * 16384 + (size_t)((kp * 4 + agp) * 64 + s) * 16 + klo * 8;
        *(u32*)dst = lo;
        *(u32*)(dst + 4) = hi;
    }
    {
        const int ch = t;
        const int chunk = m0 >> 6;
        const int kl0 = m0 & 63;
        const int klo = kl0 >> 5, agp = (kl0 & 31) >> 3;
        u32 lo = 0, hi = 0;
#pragma unroll
        for (int i = 0; i < 8; ++i) {
            u32 bb = f2e4m3(W[(m0 + i) * 256 + ch] * 16.f);
            if (i < 4) lo |= bb << (i * 8); else hi |= bb << ((i - 4) * 8);
        }
        u8* dst = WTc + chunk * 16384 + ch * 64 + agp * 16 + klo * 8;
        *(u32*)dst = lo;
        *(u32*)(dst + 4) = hi;
    }
    if (blk == 0 && t == 0) {
        loss[0] = 0.0f;
        loss[1] = -2000.0f / (2000.0f * 1999.0f);
    }
}

// ---------------- main fused kernel: 32 rows/block, 1024 blocks, TWO-PASS GEMM1 ----------------
// __launch_bounds__(512, 4): 4 waves/EU -> 2 blocks/CU, 128-VGPR cap (no acc array -> fits)
__global__ __launch_bounds__(512, 4) void main_kernel(
        const float* __restrict__ inp, const float* __restrict__ posb,
        const u8* __restrict__ Wc, const u8* __restrict__ WTc,
        const float* __restrict__ sqv, float* __restrict__ out,
        float* __restrict__ loss) {
    __shared__ __align__(16) u8 pool[POOLSZ];
    __shared__ float sPM[4][32];
    __shared__ int   sPI[4][32];
    __shared__ float sPZ[4][32];
    __shared__ float sPD[4][32];
    __shared__ float sSS[8][32];
    __shared__ float sMax[32];
    __shared__ float sThr[32];
    __shared__ float sInv[32];

    const int t = threadIdx.x;
    const int w = t >> 6, lane = t & 63;
    const int ar = lane & 15, ag = lane >> 4;
    const int blk = blockIdx.x, b = blk >> 5, hw0 = (blk & 31) << 5;
    const int prot = ((blk >> 3) & 15) * 2;      // chunk rotation for L2 spread
    const int q = w & 3, rt = w >> 2;
    const int row_a = rt * 16 + ar;

    // ---- phase A: stage xr as fp8 (x*4) at pool[0, 8448); per-row sum(x^2) ----
    {
        const int hw = t & 31, cg = t >> 5;
        const float* ip = inp + (size_t)b * 262144 + hw0 + hw;
        const float* pp = posb + hw0 + hw;
        float ss = 0.f;
        u8* xrow = pool + hw * XRS + cg * 16;
#pragma unroll
        for (int j = 0; j < 8; ++j) {
            const int ch = cg * 16 + 2 * j;
            float v0 = ip[ch * 1024] + pp[ch * 1024];
            float v1 = ip[(ch + 1) * 1024] + pp[(ch + 1) * 1024];
            ss += v0 * v0 + v1 * v1;
            u16 pk2 = (u16)(f2e4m3(v0 * 4.f) | (f2e4m3(v1 * 4.f) << 8));
            *(u16*)(xrow + 2 * j) = pk2;
        }
        ss += __shfl_xor(ss, 32);
        if (lane < 32) sSS[w][lane] = ss;
    }
    __syncthreads();

    // ---- xr B-fragments: row_a, full K=256 (8 x 8B) ----
    s64 xB[8];
#pragma unroll
    for (int kk = 0; kk < 8; ++kk)
        xB[kk] = *(const s64*)(pool + row_a * XRS + kk * 32 + ag * 8);

    const u8* wbase = Wc + ag * 1024 + (q * 16 + ar) * 16;
    const int c31 = (31 - prot) & 31;

    // ---- PASS A: stream Wc, online max/argmax/Z (no logit storage) ----
    {
        float bm = -3e38f, zz = 0.f;
        int bi = 0x7fffffff;
#pragma unroll
        for (int c = 0; c < 32; ++c) {
            const int pc = (c + prot) & 31;
            const u8* p = wbase + pc * 16384;
            s64x2 w0 = *(const s64x2*)(p);
            s64x2 w1 = *(const s64x2*)(p + 4096);
            s64x2 w2 = *(const s64x2*)(p + 8192);
            s64x2 w3 = *(const s64x2*)(p + 12288);
            f32x4 a = {0.f, 0.f, 0.f, 0.f};
            a = __builtin_amdgcn_mfma_f32_16x16x32_fp8_fp8(w0[0], xB[0], a, 0, 0, 0);
            a = __builtin_amdgcn_mfma_f32_16x16x32_fp8_fp8(w0[1], xB[1], a, 0, 0, 0);
            a = __builtin_amdgcn_mfma_f32_16x16x32_fp8_fp8(w1[0], xB[2], a, 0, 0, 0);
            a = __builtin_amdgcn_mfma_f32_16x16x32_fp8_fp8(w1[1], xB[3], a, 0, 0, 0);
            a = __builtin_amdgcn_mfma_f32_16x16x32_fp8_fp8(w2[0], xB[4], a, 0, 0, 0);
            a = __builtin_amdgcn_mfma_f32_16x16x32_fp8_fp8(w2[1], xB[5], a, 0, 0, 0);
            a = __builtin_amdgcn_mfma_f32_16x16x32_fp8_fp8(w3[0], xB[6], a, 0, 0, 0);
            a = __builtin_amdgcn_mfma_f32_16x16x32_fp8_fp8(w3[1], xB[7], a, 0, 0, 0);
            if (c == c31 && q != 0) { a[0] = -3e38f; a[1] = -3e38f; a[2] = -3e38f; a[3] = -3e38f; }
            const int cb = (pc << 6) + q * 16 + ag * 4;
            const float ob = bm;
#pragma unroll
            for (int e = 0; e < 4; ++e) {
                float v = a[e]; int id = cb + e;
                bool g = (v > bm) || (v == bm && id < bi);
                bm = g ? v : bm;
                bi = g ? id : bi;
            }
            zz *= __expf((ob - bm) * LSC);
            zz += __expf((a[0] - bm) * LSC) + __expf((a[1] - bm) * LSC)
                + __expf((a[2] - bm) * LSC) + __expf((a[3] - bm) * LSC);
        }
        // combine (m,i,z) across ag lanes with rescale
#pragma unroll
        for (int d = 16; d < 64; d <<= 1) {
            float om = __shfl_xor(bm, d);
            int   oi = __shfl_xor(bi, d);
            float oz = __shfl_xor(zz, d);
            bool g = (om > bm) || (om == bm && oi < bi);
            float nm = g ? om : bm;
            zz = zz * __expf((bm - nm) * LSC) + oz * __expf((om - nm) * LSC);
            bm = nm;
            bi = g ? oi : bi;
        }
        if (lane < 16) {
            sPM[q][rt * 16 + lane] = bm;
            sPI[q][rt * 16 + lane] = bi;
            sPZ[q][rt * 16 + lane] = zz;
        }
    }
    __syncthreads();

    // ---- combiner: final max/argmax/Z -> sMax/sThr; compact loss ----
    if (t < 32) {
        float M = sPM[0][t]; int I = sPI[0][t];
#pragma unroll
        for (int qq = 1; qq < 4; ++qq) {
            float m2 = sPM[qq][t]; int i2 = sPI[qq][t];
            bool g = (m2 > M) || (m2 == M && i2 < I);
            M = g ? m2 : M; I = g ? i2 : I;
        }
        float Z = 0.f;
#pragma unroll
        for (int qq = 0; qq < 4; ++qq) Z += sPZ[qq][t] * __expf((sPM[qq][t] - M) * LSC);
        sMax[t] = M;
        sThr[t] = 0.0025f * Z;
        float ssq = 0.f;
#pragma unroll
        for (int ww = 0; ww < 8; ++ww) ssq += sSS[ww][t];
        float term = ssq - 2.f * (M * LSC) + sqv[I];
#pragma unroll
        for (int d = 1; d < 32; d <<= 1) term += __shfl_xor(term, d);
        if (t == 0) atomicAdd(loss, term * (1.0f / 8388608.0f));
    }
    __syncthreads();

    // ---- PASS B: re-stream Wc, recompute logits, exp/mask/den, write fp8 a ----
    {
        const float M = sMax[row_a];
        const float thrv = sThr[row_a];
        const int newoff = (((q * 2 + (ag >> 1)) & 3) << 4) | ((q >> 1) << 3) | ((ag & 1) << 2);
        const int rowbase = row_a * SLSTR + newoff;
        float den = 0.f;
#pragma unroll
        for (int c = 0; c < 32; ++c) {
            const int pc = (c + prot) & 31;
            const u8* p = wbase + pc * 16384;
            s64x2 w0 = *(const s64x2*)(p);
            s64x2 w1 = *(const s64x2*)(p + 4096);
            s64x2 w2 = *(const s64x2*)(p + 8192);
            s64x2 w3 = *(const s64x2*)(p + 12288);
            f32x4 a = {0.f, 0.f, 0.f, 0.f};
            a = __builtin_amdgcn_mfma_f32_16x16x32_fp8_fp8(w0[0], xB[0], a, 0, 0, 0);
            a = __builtin_amdgcn_mfma_f32_16x16x32_fp8_fp8(w0[1], xB[1], a, 0, 0, 0);
            a = __builtin_amdgcn_mfma_f32_16x16x32_fp8_fp8(w1[0], xB[2], a, 0, 0, 0);
            a = __builtin_amdgcn_mfma_f32_16x16x32_fp8_fp8(w1[1], xB[3], a, 0, 0, 0);
            a = __builtin_amdgcn_mfma_f32_16x16x32_fp8_fp8(w2[0], xB[4], a, 0, 0, 0);
            a = __builtin_amdgcn_mfma_f32_16x16x32_fp8_fp8(w2[1], xB[5], a, 0, 0, 0);
            a = __builtin_amdgcn_mfma_f32_16x16x32_fp8_fp8(w3[0], xB[6], a, 0, 0, 0);
            a = __builtin_amdgcn_mfma_f32_16x16x32_fp8_fp8(w3[1], xB[7], a, 0, 0, 0);
            if (c == c31 && q != 0) { a[0] = -3e38f; a[1] = -3e38f; a[2] = -3e38f; a[3] = -3e38f; }
            float a0 = __expf((a[0] - M) * LSC);
            float a1 = __expf((a[1] - M) * LSC);
            float a2 = __expf((a[2] - M) * LSC);
            float a3 = __expf((a[3] - M) * LSC);
            bool k0 = a0 > thrv, k1 = a1 > thrv, k2 = a2 > thrv, k3 = a3 > thrv;
            den += (k0 ? a0 : 0.f) + (k1 ? a1 : 0.f) + (k2 ? a2 : 0.f) + (k3 ? a3 : 0.f);
            u32 pk = (k0 ? f2e4m3_fast(a0 * 64.f) : 0u)
                   | ((k1 ? f2e4m3_fast(a1 * 64.f) : 0u) << 8)
                   | ((k2 ? f2e4m3_fast(a2 * 64.f) : 0u) << 16)
                   | ((k3 ? f2e4m3_fast(a3 * 64.f) : 0u) << 24);
            *(u32*)(pool + rowbase + (pc << 6)) = pk;
        }
        den += __shfl_xor(den, 16);
        den += __shfl_xor(den, 32);
        if (lane < 16) sPD[q][rt * 16 + lane] = den;
    }
    __syncthreads();
    if (t < 32) {
        float dd = sPD[0][t] + sPD[1][t] + sPD[2][t] + sPD[3][t];
        sInv[t] = dd > 0.f ? 1.0f / (1024.0f * dd) : 0.0f;
    }
    __syncthreads();

    // ---- GEMM2: A from LDS a-matrix, B direct global->reg ----
    const int ch0 = (w * 2) * 16 + ar;
    const int ch1 = ch0 + 16;
    const u8* sLr0 = pool + ar * SLSTR + ag * 16;
    const u8* sLr1 = pool + (16 + ar) * SLSTR + ag * 16;
    const u8* wt0 = WTc + ch0 * 64 + ag * 16;
    const u8* wt1 = WTc + ch1 * 64 + ag * 16;
    f32x4 o00 = {0.f,0.f,0.f,0.f}, o01 = {0.f,0.f,0.f,0.f};
    f32x4 o10 = {0.f,0.f,0.f,0.f}, o11 = {0.f,0.f,0.f,0.f};
#pragma unroll
    for (int c = 0; c < 32; ++c) {
        const int pc = (c + prot) & 31;
        const int cc64 = pc << 6;
        s64x2 B0 = *(const s64x2*)(wt0 + pc * 16384);
        s64x2 B1 = *(const s64x2*)(wt1 + pc * 16384);
        s64x2 A0 = *(const s64x2*)(sLr0 + cc64);
        s64x2 A1 = *(const s64x2*)(sLr1 + cc64);
        o00 = __builtin_amdgcn_mfma_f32_16x16x32_fp8_fp8(A0[0], B0[0], o00, 0, 0, 0);
        o00 = __builtin_amdgcn_mfma_f32_16x16x32_fp8_fp8(A0[1], B0[1], o00, 0, 0, 0);
        o01 = __builtin_amdgcn_mfma_f32_16x16x32_fp8_fp8(A1[0], B0[0], o01, 0, 0, 0);
        o01 = __builtin_amdgcn_mfma_f32_16x16x32_fp8_fp8(A1[1], B0[1], o01, 0, 0, 0);
        o10 = __builtin_amdgcn_mfma_f32_16x16x32_fp8_fp8(A0[0], B1[0], o10, 0, 0, 0);
        o10 = __builtin_amdgcn_mfma_f32_16x16x32_fp8_fp8(A0[1], B1[1], o10, 0, 0, 0);
        o11 = __builtin_amdgcn_mfma_f32_16x16x32_fp8_fp8(A1[0], B1[0], o11, 0, 0, 0);
        o11 = __builtin_amdgcn_mfma_f32_16x16x32_fp8_fp8(A1[1], B1[1], o11, 0, 0, 0);
    }
    __syncthreads();   // all a-reads done; reuse pool as f32 out-stage

    {
        float* sO = (float*)pool;
#pragma unroll
        for (int i = 0; i < 4; ++i) {
            int r0 = ag * 4 + i, r1 = 16 + ag * 4 + i;
            sO[r0 * OSTR + ch0] = o00[i] * sInv[r0];
            sO[r1 * OSTR + ch0] = o01[i] * sInv[r1];
            sO[r0 * OSTR + ch1] = o10[i] * sInv[r0];
            sO[r1 * OSTR + ch1] = o11[i] * sInv[r1];
        }
    }
    __syncthreads();
    {
        const float* sO = (const float*)pool;
        const int hw = t & 31, cq = t >> 5;
        float* op = out + (size_t)b * 262144 + hw0 + hw;
#pragma unroll
        for (int i = 0; i < 16; ++i) {
            int ch = cq + (i << 4);
            op[ch * 1024] = sO[hw * OSTR + ch];
        }
    }
}

// ---------------- distance loss from fp8 Wc (paired-k layout) ----------------
__global__ __launch_bounds__(256) void dist_kernel(const u8* __restrict__ Wc,
                                                   const float* __restrict__ sqv,
                                                   float* __restrict__ dl) {
    __shared__ float red[4];
    int t = threadIdx.x, w = t >> 6, lane = t & 63;
    int ar = lane & 15, ag = lane >> 4;
    const int i0 = blockIdx.x << 4;
    const int ci = i0 >> 6, si0 = i0 & 63;
    s64x2 af2[4];
#pragma unroll
    for (int kp = 0; kp < 4; ++kp)
        af2[kp] = *(const s64x2*)(Wc + ci * 16384 + (size_t)((kp * 4 + ag) * 64 + si0 + ar) * 16);
    float sqi[4];
#pragma unroll
    for (int e = 0; e < 4; ++e) sqi[e] = sqv[i0 + ag * 4 + e];
    float sum = 0.f;
    for (int jt = w; jt < 125; jt += 4) {
        const int j0 = jt << 4;
        const int cj = j0 >> 6, sj0 = j0 & 63;
        f32x4 acc = {0.f, 0.f, 0.f, 0.f};
#pragma unroll
        for (int kp = 0; kp < 4; ++kp) {
            s64x2 bf = *(const s64x2*)(Wc + cj * 16384 + (size_t)((kp * 4 + ag) * 64 + sj0 + ar) * 16);
            acc = __builtin_amdgcn_mfma_f32_16x16x32_fp8_fp8(af2[kp][0], bf[0], acc, 0, 0, 0);
            acc = __builtin_amdgcn_mfma_f32_16x16x32_fp8_fp8(af2[kp][1], bf[1], acc, 0, 0, 0);
        }
        float sqj = sqv[j0 + ar];
#pragma unroll
        for (int e = 0; e < 4; ++e) {
            float dist = 1.0f - (sqi[e] + sqj - acc[e] * 0.0078125f);
            sum += dist > 0.f ? dist : 0.f;
        }
    }
#pragma unroll
    for (int d = 1; d < 64; d <<= 1) sum += __shfl_xor(sum, d);
    if (lane == 0) red[w] = sum;
    __syncthreads();
    if (t == 0) {
        float s = red[0] + red[1] + red[2] + red[3];
        atomicAdd(dl, s * (1.0f / (2000.0f * 1999.0f)));
    }
}

extern "C" void kernel_launch(void* const* d_in, const int* in_sizes, int n_in,
                              void* d_out, int out_size, void* d_ws, size_t ws_size,
                              hipStream_t stream) {
    (void)in_sizes; (void)n_in; (void)out_size; (void)ws_size;
    const float* inp  = (const float*)d_in[0];
    const float* W    = (const float*)d_in[2];
    const float* posb = (const float*)d_in[3];
    float* out = (float*)d_out;

    u8* WTc = (u8*)d_ws;                                     // 32*16384 = 524,288 B
    u8* Wc  = (u8*)d_ws + 524288;                            // 32*16384 = 524,288 B
    float* sqv = (float*)((u8*)d_ws + 1048576);              // 2000*4   =   8,000 B

    hipLaunchKernelGGL(prep_kernel, dim3(250), dim3(256), 0, stream, W, WTc, Wc, sqv, out + OUTN);
    hipLaunchKernelGGL(main_kernel, dim3(1024), dim3(512), 0, stream, inp, posb, Wc, WTc, sqv, out, out + OUTN);
    hipLaunchKernelGGL(dist_kernel, dim3(125), dim3(256), 0, stream, Wc, sqv, out + OUTN + 1);
}

// Round 13
// 148.206 us; speedup vs baseline: 2.5877x; 2.5877x over previous
//
#include <hip/hip_runtime.h>
#include <hip/hip_bf16.h>

typedef unsigned char u8;
typedef unsigned short u16;
typedef unsigned int u32;
typedef long long s64;
typedef float f32x4 __attribute__((ext_vector_type(4)));
typedef long long s64x2 __attribute__((ext_vector_type(2)));

#define MEM    2000
#define FEA    256
#define SLSTR  2064      // fp8 a row stride (bytes), 16B-aligned
#define OSTR   265       // out-stage row stride (f32)
#define XRS    264       // xr fp8 row stride (bytes)
#define POOLSZ 66048     // a-matrix 32*SLSTR; xr + out-stage overlap inside
#define OUTN   8388608   // 32*256*32*32
#define LSC    0.015625f // logit scale: logit = acc * LSC

// exact f32 -> e4m3fn (RNE) incl subnormals
__device__ __forceinline__ u32 f2e4m3(float x) {
    float ax = fabsf(x);
    u32 s = (__builtin_bit_cast(u32, x) >> 24) & 0x80u;
    if (ax >= 448.f) return s | 0x7e;
    if (ax < 0.015625f) {
        int q = (int)rintf(ax * 512.f);
        return s | (u32)q;
    }
    int e = (int)(__builtin_bit_cast(u32, ax) >> 23) - 127;
    float scale = __builtin_bit_cast(float, (u32)((127 - e + 3) << 23));
    int q = (int)rintf(ax * scale);
    int E = e + 7;
    if (q == 16) { q = 8; E += 1; if (E > 15) return s | 0x7e; }
    return s | (u32)(E << 3) | (u32)(q & 7);
}
// fast f32 -> e4m3fn for v in {0} U [0.15, 64]
__device__ __forceinline__ u32 f2e4m3_fast(float v) {
    u32 u = __builtin_bit_cast(u32, v);
    u += 0x0007FFFFu + ((u >> 20) & 1u);
    int bb = (int)(u >> 20) - 0x3C0;
    return bb < 0 ? 0u : (u32)bb;
}

// ---------------- prep (identical to round 10) ----------------
__global__ __launch_bounds__(256) void prep_kernel(const float* __restrict__ W,
                                                   u8* __restrict__ WTc,
                                                   u8* __restrict__ Wc,
                                                   float* __restrict__ sqv,
                                                   float* __restrict__ loss) {
    const int blk = blockIdx.x, t = threadIdx.x;
    const int m0 = blk * 8;
    {
        const int sl = t >> 5, cl = t & 31;
        const int slot = m0 + sl;
        const int ch0 = cl * 8;
        const float* wr = W + slot * 256 + ch0;
        f32x4 v0 = *(const f32x4*)wr;
        f32x4 v1 = *(const f32x4*)(wr + 4);
        float ss = v0[0]*v0[0] + v0[1]*v0[1] + v0[2]*v0[2] + v0[3]*v0[3]
                 + v1[0]*v1[0] + v1[1]*v1[1] + v1[2]*v1[2] + v1[3]*v1[3];
        ss += __shfl_xor(ss, 1); ss += __shfl_xor(ss, 2); ss += __shfl_xor(ss, 4);
        ss += __shfl_xor(ss, 8); ss += __shfl_xor(ss, 16);
        if (cl == 0) sqv[slot] = ss;
        const int c = slot >> 6, s = slot & 63;
        const int kk = cl >> 2, agp = cl & 3;
        const int kp = kk >> 1, klo = kk & 1;
        u32 lo = 0, hi = 0;
#pragma unroll
        for (int i = 0; i < 4; ++i) {
            lo |= f2e4m3(v0[i] * 16.f) << (i * 8);
            hi |= f2e4m3(v1[i] * 16.f) << (i * 8);
        }
        u8* dst = Wc + c * 16384 + (size_t)((kp * 4 + agp) * 64 + s) * 16 + klo * 8;
        *(u32*)dst = lo;
        *(u32*)(dst + 4) = hi;
    }
    {
        const int ch = t;
        const int chunk = m0 >> 6;
        const int kl0 = m0 & 63;
        const int klo = kl0 >> 5, agp = (kl0 & 31) >> 3;
        u32 lo = 0, hi = 0;
#pragma unroll
        for (int i = 0; i < 8; ++i) {
            u32 bb = f2e4m3(W[(m0 + i) * 256 + ch] * 16.f);
            if (i < 4) lo |= bb << (i * 8); else hi |= bb << ((i - 4) * 8);
        }
        u8* dst = WTc + chunk * 16384 + ch * 64 + agp * 16 + klo * 8;
        *(u32*)dst = lo;
        *(u32*)(dst + 4) = hi;
    }
    if (blk == 0 && t == 0) {
        loss[0] = 0.0f;
        loss[1] = -2000.0f / (2000.0f * 1999.0f);
    }
}

// ---------------- main fused kernel: 32 rows/block, 1024 blocks, TWO-PASS GEMM1 ----------------
// waves_per_eu(4,4): pinned 4 waves/EU -> 128-VGPR budget, 2 blocks/CU (LDS 69.6KB x2 fits)
__global__ __attribute__((amdgpu_flat_work_group_size(512, 512), amdgpu_waves_per_eu(4, 4)))
void main_kernel(
        const float* __restrict__ inp, const float* __restrict__ posb,
        const u8* __restrict__ Wc, const u8* __restrict__ WTc,
        const float* __restrict__ sqv, float* __restrict__ out,
        float* __restrict__ loss) {
    __shared__ __align__(16) u8 pool[POOLSZ];
    __shared__ float sPM[4][32];
    __shared__ int   sPI[4][32];
    __shared__ float sPZ[4][32];
    __shared__ float sPD[4][32];
    __shared__ float sSS[8][32];
    __shared__ float sMax[32];
    __shared__ float sThr[32];
    __shared__ float sInv[32];

    const int t = threadIdx.x;
    const int w = t >> 6, lane = t & 63;
    const int ar = lane & 15, ag = lane >> 4;
    const int blk = blockIdx.x, b = blk >> 5, hw0 = (blk & 31) << 5;
    const int prot = ((blk >> 3) & 15) * 2;      // chunk rotation for L2 spread
    const int q = w & 3, rt = w >> 2;
    const int row_a = rt * 16 + ar;

    // ---- phase A: stage xr as fp8 (x*4) at pool[0, 8448); per-row sum(x^2) ----
    {
        const int hw = t & 31, cg = t >> 5;
        const float* ip = inp + (size_t)b * 262144 + hw0 + hw;
        const float* pp = posb + hw0 + hw;
        float ss = 0.f;
        u8* xrow = pool + hw * XRS + cg * 16;
#pragma unroll
        for (int j = 0; j < 8; ++j) {
            const int ch = cg * 16 + 2 * j;
            float v0 = ip[ch * 1024] + pp[ch * 1024];
            float v1 = ip[(ch + 1) * 1024] + pp[(ch + 1) * 1024];
            ss += v0 * v0 + v1 * v1;
            u16 pk2 = (u16)(f2e4m3(v0 * 4.f) | (f2e4m3(v1 * 4.f) << 8));
            *(u16*)(xrow + 2 * j) = pk2;
        }
        ss += __shfl_xor(ss, 32);
        if (lane < 32) sSS[w][lane] = ss;
    }
    __syncthreads();

    // ---- xr B-fragments: row_a, full K=256 (8 x 8B) ----
    s64 xB[8];
#pragma unroll
    for (int kk = 0; kk < 8; ++kk)
        xB[kk] = *(const s64*)(pool + row_a * XRS + kk * 32 + ag * 8);

    const u8* wbase = Wc + ag * 1024 + (q * 16 + ar) * 16;
    const int c31 = (31 - prot) & 31;

    // ---- PASS A: stream Wc, online max/argmax/Z (no logit storage) ----
    {
        float bm = -3e38f, zz = 0.f;
        int bi = 0x7fffffff;
#pragma unroll 4
        for (int c = 0; c < 32; ++c) {
            const int pc = (c + prot) & 31;
            const u8* p = wbase + pc * 16384;
            s64x2 w0 = *(const s64x2*)(p);
            s64x2 w1 = *(const s64x2*)(p + 4096);
            s64x2 w2 = *(const s64x2*)(p + 8192);
            s64x2 w3 = *(const s64x2*)(p + 12288);
            f32x4 a = {0.f, 0.f, 0.f, 0.f};
            a = __builtin_amdgcn_mfma_f32_16x16x32_fp8_fp8(w0[0], xB[0], a, 0, 0, 0);
            a = __builtin_amdgcn_mfma_f32_16x16x32_fp8_fp8(w0[1], xB[1], a, 0, 0, 0);
            a = __builtin_amdgcn_mfma_f32_16x16x32_fp8_fp8(w1[0], xB[2], a, 0, 0, 0);
            a = __builtin_amdgcn_mfma_f32_16x16x32_fp8_fp8(w1[1], xB[3], a, 0, 0, 0);
            a = __builtin_amdgcn_mfma_f32_16x16x32_fp8_fp8(w2[0], xB[4], a, 0, 0, 0);
            a = __builtin_amdgcn_mfma_f32_16x16x32_fp8_fp8(w2[1], xB[5], a, 0, 0, 0);
            a = __builtin_amdgcn_mfma_f32_16x16x32_fp8_fp8(w3[0], xB[6], a, 0, 0, 0);
            a = __builtin_amdgcn_mfma_f32_16x16x32_fp8_fp8(w3[1], xB[7], a, 0, 0, 0);
            if (c == c31 && q != 0) { a[0] = -3e38f; a[1] = -3e38f; a[2] = -3e38f; a[3] = -3e38f; }
            const int cb = (pc << 6) + q * 16 + ag * 4;
            const float ob = bm;
#pragma unroll
            for (int e = 0; e < 4; ++e) {
                float v = a[e]; int id = cb + e;
                bool g = (v > bm) || (v == bm && id < bi);
                bm = g ? v : bm;
                bi = g ? id : bi;
            }
            zz *= __expf((ob - bm) * LSC);
            zz += __expf((a[0] - bm) * LSC) + __expf((a[1] - bm) * LSC)
                + __expf((a[2] - bm) * LSC) + __expf((a[3] - bm) * LSC);
        }
        // combine (m,i,z) across ag lanes with rescale
#pragma unroll
        for (int d = 16; d < 64; d <<= 1) {
            float om = __shfl_xor(bm, d);
            int   oi = __shfl_xor(bi, d);
            float oz = __shfl_xor(zz, d);
            bool g = (om > bm) || (om == bm && oi < bi);
            float nm = g ? om : bm;
            zz = zz * __expf((bm - nm) * LSC) + oz * __expf((om - nm) * LSC);
            bm = nm;
            bi = g ? oi : bi;
        }
        if (lane < 16) {
            sPM[q][rt * 16 + lane] = bm;
            sPI[q][rt * 16 + lane] = bi;
            sPZ[q][rt * 16 + lane] = zz;
        }
    }
    __syncthreads();

    // ---- combiner: final max/argmax/Z -> sMax/sThr; compact loss ----
    if (t < 32) {
        float M = sPM[0][t]; int I = sPI[0][t];
#pragma unroll
        for (int qq = 1; qq < 4; ++qq) {
            float m2 = sPM[qq][t]; int i2 = sPI[qq][t];
            bool g = (m2 > M) || (m2 == M && i2 < I);
            M = g ? m2 : M; I = g ? i2 : I;
        }
        float Z = 0.f;
#pragma unroll
        for (int qq = 0; qq < 4; ++qq) Z += sPZ[qq][t] * __expf((sPM[qq][t] - M) * LSC);
        sMax[t] = M;
        sThr[t] = 0.0025f * Z;
        float ssq = 0.f;
#pragma unroll
        for (int ww = 0; ww < 8; ++ww) ssq += sSS[ww][t];
        float term = ssq - 2.f * (M * LSC) + sqv[I];
#pragma unroll
        for (int d = 1; d < 32; d <<= 1) term += __shfl_xor(term, d);
        if (t == 0) atomicAdd(loss, term * (1.0f / 8388608.0f));
    }
    __syncthreads();

    // ---- PASS B: re-stream Wc, recompute logits, exp/mask/den, write fp8 a ----
    {
        const float M = sMax[row_a];
        const float thrv = sThr[row_a];
        const int newoff = (((q * 2 + (ag >> 1)) & 3) << 4) | ((q >> 1) << 3) | ((ag & 1) << 2);
        const int rowbase = row_a * SLSTR + newoff;
        float den = 0.f;
#pragma unroll 4
        for (int c = 0; c < 32; ++c) {
            const int pc = (c + prot) & 31;
            const u8* p = wbase + pc * 16384;
            s64x2 w0 = *(const s64x2*)(p);
            s64x2 w1 = *(const s64x2*)(p + 4096);
            s64x2 w2 = *(const s64x2*)(p + 8192);
            s64x2 w3 = *(const s64x2*)(p + 12288);
            f32x4 a = {0.f, 0.f, 0.f, 0.f};
            a = __builtin_amdgcn_mfma_f32_16x16x32_fp8_fp8(w0[0], xB[0], a, 0, 0, 0);
            a = __builtin_amdgcn_mfma_f32_16x16x32_fp8_fp8(w0[1], xB[1], a, 0, 0, 0);
            a = __builtin_amdgcn_mfma_f32_16x16x32_fp8_fp8(w1[0], xB[2], a, 0, 0, 0);
            a = __builtin_amdgcn_mfma_f32_16x16x32_fp8_fp8(w1[1], xB[3], a, 0, 0, 0);
            a = __builtin_amdgcn_mfma_f32_16x16x32_fp8_fp8(w2[0], xB[4], a, 0, 0, 0);
            a = __builtin_amdgcn_mfma_f32_16x16x32_fp8_fp8(w2[1], xB[5], a, 0, 0, 0);
            a = __builtin_amdgcn_mfma_f32_16x16x32_fp8_fp8(w3[0], xB[6], a, 0, 0, 0);
            a = __builtin_amdgcn_mfma_f32_16x16x32_fp8_fp8(w3[1], xB[7], a, 0, 0, 0);
            if (c == c31 && q != 0) { a[0] = -3e38f; a[1] = -3e38f; a[2] = -3e38f; a[3] = -3e38f; }
            float a0 = __expf((a[0] - M) * LSC);
            float a1 = __expf((a[1] - M) * LSC);
            float a2 = __expf((a[2] - M) * LSC);
            float a3 = __expf((a[3] - M) * LSC);
            bool k0 = a0 > thrv, k1 = a1 > thrv, k2 = a2 > thrv, k3 = a3 > thrv;
            den += (k0 ? a0 : 0.f) + (k1 ? a1 : 0.f) + (k2 ? a2 : 0.f) + (k3 ? a3 : 0.f);
            u32 pk = (k0 ? f2e4m3_fast(a0 * 64.f) : 0u)
                   | ((k1 ? f2e4m3_fast(a1 * 64.f) : 0u) << 8)
                   | ((k2 ? f2e4m3_fast(a2 * 64.f) : 0u) << 16)
                   | ((k3 ? f2e4m3_fast(a3 * 64.f) : 0u) << 24);
            *(u32*)(pool + rowbase + (pc << 6)) = pk;
        }
        den += __shfl_xor(den, 16);
        den += __shfl_xor(den, 32);
        if (lane < 16) sPD[q][rt * 16 + lane] = den;
    }
    __syncthreads();
    if (t < 32) {
        float dd = sPD[0][t] + sPD[1][t] + sPD[2][t] + sPD[3][t];
        sInv[t] = dd > 0.f ? 1.0f / (1024.0f * dd) : 0.0f;
    }
    __syncthreads();

    // ---- GEMM2: A from LDS a-matrix, B direct global->reg ----
    const int ch0 = (w * 2) * 16 + ar;
    const int ch1 = ch0 + 16;
    const u8* sLr0 = pool + ar * SLSTR + ag * 16;
    const u8* sLr1 = pool + (16 + ar) * SLSTR + ag * 16;
    const u8* wt0 = WTc + ch0 * 64 + ag * 16;
    const u8* wt1 = WTc + ch1 * 64 + ag * 16;
    f32x4 o00 = {0.f,0.f,0.f,0.f}, o01 = {0.f,0.f,0.f,0.f};
    f32x4 o10 = {0.f,0.f,0.f,0.f}, o11 = {0.f,0.f,0.f,0.f};
#pragma unroll 4
    for (int c = 0; c < 32; ++c) {
        const int pc = (c + prot) & 31;
        const int cc64 = pc << 6;
        s64x2 B0 = *(const s64x2*)(wt0 + pc * 16384);
        s64x2 B1 = *(const s64x2*)(wt1 + pc * 16384);
        s64x2 A0 = *(const s64x2*)(sLr0 + cc64);
        s64x2 A1 = *(const s64x2*)(sLr1 + cc64);
        o00 = __builtin_amdgcn_mfma_f32_16x16x32_fp8_fp8(A0[0], B0[0], o00, 0, 0, 0);
        o00 = __builtin_amdgcn_mfma_f32_16x16x32_fp8_fp8(A0[1], B0[1], o00, 0, 0, 0);
        o01 = __builtin_amdgcn_mfma_f32_16x16x32_fp8_fp8(A1[0], B0[0], o01, 0, 0, 0);
        o01 = __builtin_amdgcn_mfma_f32_16x16x32_fp8_fp8(A1[1], B0[1], o01, 0, 0, 0);
        o10 = __builtin_amdgcn_mfma_f32_16x16x32_fp8_fp8(A0[0], B1[0], o10, 0, 0, 0);
        o10 = __builtin_amdgcn_mfma_f32_16x16x32_fp8_fp8(A0[1], B1[1], o10, 0, 0, 0);
        o11 = __builtin_amdgcn_mfma_f32_16x16x32_fp8_fp8(A1[0], B1[0], o11, 0, 0, 0);
        o11 = __builtin_amdgcn_mfma_f32_16x16x32_fp8_fp8(A1[1], B1[1], o11, 0, 0, 0);
    }
    __syncthreads();   // all a-reads done; reuse pool as f32 out-stage

    {
        float* sO = (float*)pool;
#pragma unroll
        for (int i = 0; i < 4; ++i) {
            int r0 = ag * 4 + i, r1 = 16 + ag * 4 + i;
            sO[r0 * OSTR + ch0] = o00[i] * sInv[r0];
            sO[r1 * OSTR + ch0] = o01[i] * sInv[r1];
            sO[r0 * OSTR + ch1] = o10[i] * sInv[r0];
            sO[r1 * OSTR + ch1] = o11[i] * sInv[r1];
        }
    }
    __syncthreads();
    {
        const float* sO = (const float*)pool;
        const int hw = t & 31, cq = t >> 5;
        float* op = out + (size_t)b * 262144 + hw0 + hw;
#pragma unroll
        for (int i = 0; i < 16; ++i) {
            int ch = cq + (i << 4);
            op[ch * 1024] = sO[hw * OSTR + ch];
        }
    }
}

// ---------------- distance loss from fp8 Wc (paired-k layout) ----------------
__global__ __launch_bounds__(256) void dist_kernel(const u8* __restrict__ Wc,
                                                   const float* __restrict__ sqv,
                                                   float* __restrict__ dl) {
    __shared__ float red[4];
    int t = threadIdx.x, w = t >> 6, lane = t & 63;
    int ar = lane & 15, ag = lane >> 4;
    const int i0 = blockIdx.x << 4;
    const int ci = i0 >> 6, si0 = i0 & 63;
    s64x2 af2[4];
#pragma unroll
    for (int kp = 0; kp < 4; ++kp)
        af2[kp] = *(const s64x2*)(Wc + ci * 16384 + (size_t)((kp * 4 + ag) * 64 + si0 + ar) * 16);
    float sqi[4];
#pragma unroll
    for (int e = 0; e < 4; ++e) sqi[e] = sqv[i0 + ag * 4 + e];
    float sum = 0.f;
    for (int jt = w; jt < 125; jt += 4) {
        const int j0 = jt << 4;
        const int cj = j0 >> 6, sj0 = j0 & 63;
        f32x4 acc = {0.f, 0.f, 0.f, 0.f};
#pragma unroll
        for (int kp = 0; kp < 4; ++kp) {
            s64x2 bf = *(const s64x2*)(Wc + cj * 16384 + (size_t)((kp * 4 + ag) * 64 + sj0 + ar) * 16);
            acc = __builtin_amdgcn_mfma_f32_16x16x32_fp8_fp8(af2[kp][0], bf[0], acc, 0, 0, 0);
            acc = __builtin_amdgcn_mfma_f32_16x16x32_fp8_fp8(af2[kp][1], bf[1], acc, 0, 0, 0);
        }
        float sqj = sqv[j0 + ar];
#pragma unroll
        for (int e = 0; e < 4; ++e) {
            float dist = 1.0f - (sqi[e] + sqj - acc[e] * 0.0078125f);
            sum += dist > 0.f ? dist : 0.f;
        }
    }
#pragma unroll
    for (int d = 1; d < 64; d <<= 1) sum += __shfl_xor(sum, d);
    if (lane == 0) red[w] = sum;
    __syncthreads();
    if (t == 0) {
        float s = red[0] + red[1] + red[2] + red[3];
        atomicAdd(dl, s * (1.0f / (2000.0f * 1999.0f)));
    }
}

extern "C" void kernel_launch(void* const* d_in, const int* in_sizes, int n_in,
                              void* d_out, int out_size, void* d_ws, size_t ws_size,
                              hipStream_t stream) {
    (void)in_sizes; (void)n_in; (void)out_size; (void)ws_size;
    const float* inp  = (const float*)d_in[0];
    const float* W    = (const float*)d_in[2];
    const float* posb = (const float*)d_in[3];
    float* out = (float*)d_out;

    u8* WTc = (u8*)d_ws;                                     // 32*16384 = 524,288 B
    u8* Wc  = (u8*)d_ws + 524288;                            // 32*16384 = 524,288 B
    float* sqv = (float*)((u8*)d_ws + 1048576);              // 2000*4   =   8,000 B

    hipLaunchKernelGGL(prep_kernel, dim3(250), dim3(256), 0, stream, W, WTc, Wc, sqv, out + OUTN);
    hipLaunchKernelGGL(main_kernel, dim3(1024), dim3(512), 0, stream, inp, posb, Wc, WTc, sqv, out, out + OUTN);
    hipLaunchKernelGGL(dist_kernel, dim3(125), dim3(256), 0, stream, Wc, sqv, out + OUTN + 1);
}